// Round 17
// baseline (162.004 us; speedup 1.0000x reference)
//
#include <hip/hip_runtime.h>

typedef _Float16 half8 __attribute__((ext_vector_type(8)));
typedef float floatx16 __attribute__((ext_vector_type(16)));

#define TPB    256            // 4 waves
#define QPB    256            // queries per block (64 per wave: 2 groups x 32)
#define CHUNK  1024           // db points per block (single-shot staged)
#define NTILE  (CHUNK / 32)   // 32 tiles of 32 db points
#define SMH    (CHUNK * 16)   // 16384 halfs = 32 KiB

// 32x32x16 f16 MFMA, SWAPPED-OPERAND form (R6): db points are the A operand
// (rows), queries are the B operand (cols). D col = lane&31 = query.
// R17: ELEMENTWISE VECTOR-MIN ACCUMULATION. All prior stall levers are proven
// null (occupancy R10, barriers R10, MFMA-latency lag R14, DS prefetch depth
// R15, min encoding R13, grain R16 modest). Last untested dataflow serializer:
// the per-MFMA fold TREE (17 ops, 5 dependency levels, re-serialized by the
// scheduler right after its producer — R14/R15 showed source-level lagging is
// collapsed). Replace with rv[i] = min(rv[i], d[i]): 16 INDEPENDENT ops per
// MFMA (same 1.0 min/distance), carried dep is one-tile-old rv. The 16->1
// tree runs ONCE at kernel end. Costs 16 VGPRs per query group -> 2 groups.
// R16 lesson: grain amortization works (first gain since R6); keep 1 ds_read
//   feeding multiple MFMAs.
// R13 lesson (FMIN null): fminf already minnum; 1 min/distance is the floor.
// R7 lesson (FAILED): inline asm must never READ MFMA results (hazard gap).
// R9 lesson (REGRESSED): inline-asm v_min3 -> constraint copy-storm. NO asm.
// R4 lesson: no __launch_bounds__(256,8) — reg budget collapse -> spill.
// R3 lesson: watch total live floatx16; here rv0+rv1 (32) + <=2 transient d.
// R1 lesson: staging data in named scalars only; ext_vector indices constant.
// Block = 256 queries x ONE md-chunk (1024 db points); partial per-query mins
// -> ws[chunk][dir][b][q]; chamfer_reduce mins over chunks + mean.
// K-slots (11 of 16): A(db): (xh,xl,xh,yh,yl,yh,zh,zl | zh,hqh,hql,0..)
//                     B(qry): (-xh,-xh,-xl,-yh,-yh,-yl,-zh,-zh | -zl,1,1,0..)
// => acc = 0.5||q_db||^2 - p.q_db (split-f16); dist = 2*(0.5||p||^2 + min acc).
// A: row = lane&31, k = (lane>>5)*8+j.  B: col = lane&31, same k.
// C/D: col = lane&31 (query), row(db) = (reg&3)+8*(reg>>2)+4*(lane>>5)
//   -> regs cover 16 of 32 db rows; h-partner lane covers the other 16.

#define FMIN __builtin_fminf   // llvm.minnum: single v_min_f32

// elementwise running min: 16 independent v_min_f32 (no tree, no chain)
__device__ __forceinline__ floatx16 vmin16(floatx16 a, floatx16 d) {
#pragma unroll
    for (int i = 0; i < 16; ++i) a[i] = FMIN(a[i], d[i]);
    return a;
}

// final 16 -> 1 tree (once per kernel)
__device__ __forceinline__ float fold16(floatx16 d) {
    float m0 = FMIN(FMIN(d[0],  d[1]),  d[2]);
    float m1 = FMIN(FMIN(d[3],  d[4]),  d[5]);
    float m2 = FMIN(FMIN(d[6],  d[7]),  d[8]);
    float m3 = FMIN(FMIN(d[9],  d[10]), d[11]);
    float m4 = FMIN(FMIN(d[12], d[13]), d[14]);
    float n0 = FMIN(FMIN(m0, m1), m2);
    float n1 = FMIN(FMIN(m3, m4), d[15]);
    return FMIN(n0, n1);
}

__device__ __forceinline__ void wr_point(_Float16* __restrict__ smb, int j,
                                         float x, float y, float z) {
    float hq = 0.5f * (x * x + y * y + z * z);
    _Float16 xh = (_Float16)x, yh = (_Float16)y, zh = (_Float16)z;
    _Float16 xl = (_Float16)(x - (float)xh);
    _Float16 yl = (_Float16)(y - (float)yh);
    _Float16 zl = (_Float16)(z - (float)zh);
    _Float16 qh = (_Float16)hq;
    _Float16 ql = (_Float16)(hq - (float)qh);
    const _Float16 hz = (_Float16)0.0f;
    int t = j >> 5, c = j & 31;
    half8 v0, v1;
    v0[0] = xh; v0[1] = xl; v0[2] = xh; v0[3] = yh;
    v0[4] = yl; v0[5] = yh; v0[6] = zh; v0[7] = zl;
    v1[0] = zh; v1[1] = qh; v1[2] = ql; v1[3] = hz;
    v1[4] = hz; v1[5] = hz; v1[6] = hz; v1[7] = hz;
    *(half8*)&smb[t * 512 + c * 8]       = v0;   // k-half 0
    *(half8*)&smb[t * 512 + 256 + c * 8] = v1;   // k-half 1
}

__global__ __launch_bounds__(TPB, 4) void chamfer_mfma(const float* __restrict__ xyz1,
                                                       const float* __restrict__ xyz2,
                                                       float* __restrict__ ws,
                                                       int N, int M, int QCAP,
                                                       int nchunks) {
    const int b = blockIdx.y, dir = blockIdx.z;
    const int B = gridDim.y;
    const int qblock = (int)blockIdx.x / nchunks;
    const int chunk  = (int)blockIdx.x % nchunks;
    const float* __restrict__ P = dir ? xyz2 + (size_t)b * M * 3 : xyz1 + (size_t)b * N * 3;
    const float* __restrict__ Q = dir ? xyz1 + (size_t)b * N * 3 : xyz2 + (size_t)b * M * 3;
    const int nq = dir ? M : N;
    const int md = dir ? N : M;

    if (qblock * QPB >= nq) return;   // block-uniform, before any barrier

    const int base = chunk * CHUNK;   // clamp-pad covers base+CHUNK > md

    __shared__ __align__(16) _Float16 smB[SMH];

    const int tid = (int)threadIdx.x;
    const int w   = tid >> 6;
    const int l   = tid & 63;
    const int m   = l & 31;      // B col (query) this lane serves
    const int h   = l >> 5;      // k-half: k = h*8 + j

    const _Float16 hz = (_Float16)0.0f, hone = (_Float16)1.0f;
    const int qb = qblock * QPB + w * 64;    // wave owns 64 queries (2 x 32)

    // ---- Build the wave's 2 query B-fragments (held for the whole kernel) ----
    half8 qfr[2];
#pragma unroll
    for (int g = 0; g < 2; ++g) {
        int idx = qb + g * 32 + m;
        int ci  = idx < nq ? idx : nq - 1;
        float x = P[3 * ci], y = P[3 * ci + 1], z = P[3 * ci + 2];
        _Float16 xh = (_Float16)x, yh = (_Float16)y, zh = (_Float16)z;
        _Float16 xl = (_Float16)(x - (float)xh);
        _Float16 yl = (_Float16)(y - (float)yh);
        _Float16 zl = (_Float16)(z - (float)zh);
        half8 a;
        if (h == 0) {
            a[0] = -xh; a[1] = -xh; a[2] = -xl; a[3] = -yh;
            a[4] = -yh; a[5] = -yl; a[6] = -zh; a[7] = -zh;
        } else {
            a[0] = -zl; a[1] = hone; a[2] = hone; a[3] = hz;
            a[4] = hz;  a[5] = hz;   a[6] = hz;  a[7] = hz;
        }
        qfr[g] = a;
    }

    // ---- Stage the whole 1024-pt chunk once (4 pts/thread, named scalars) ----
    {
        int g0 = base + tid;
        int g1 = base + tid + 256;
        int g2 = base + tid + 512;
        int g3 = base + tid + 768;
        g0 = g0 < md ? g0 : md - 1;   // clamp-pad: dups never change a min
        g1 = g1 < md ? g1 : md - 1;
        g2 = g2 < md ? g2 : md - 1;
        g3 = g3 < md ? g3 : md - 1;
        float x0 = Q[3 * g0], y0 = Q[3 * g0 + 1], z0 = Q[3 * g0 + 2];
        float x1 = Q[3 * g1], y1 = Q[3 * g1 + 1], z1 = Q[3 * g1 + 2];
        float x2 = Q[3 * g2], y2 = Q[3 * g2 + 1], z2 = Q[3 * g2 + 2];
        float x3 = Q[3 * g3], y3 = Q[3 * g3 + 1], z3 = Q[3 * g3 + 2];
        wr_point(smB, tid,       x0, y0, z0);
        wr_point(smB, tid + 256, x1, y1, z1);
        wr_point(smB, tid + 512, x2, y2, z2);
        wr_point(smB, tid + 768, x3, y3, z3);
    }
    __syncthreads();    // the kernel's ONLY barrier

    const floatx16 czero = {0.0f, 0.0f, 0.0f, 0.0f, 0.0f, 0.0f, 0.0f, 0.0f,
                            0.0f, 0.0f, 0.0f, 0.0f, 0.0f, 0.0f, 0.0f, 0.0f};
    floatx16 rv0, rv1;                       // running vector mins per group
#pragma unroll
    for (int i = 0; i < 16; ++i) { rv0[i] = 3.0e38f; rv1[i] = 3.0e38f; }

    // ---- Sweep 32 tiles: 1 ds_read (1-ahead) + 2 MFMA + 32 independent mins ----
    const _Float16* bp = &smB[h * 256 + m * 8];
    half8 cur = *(const half8*)(bp);
#pragma unroll 1
    for (int t = 0; t < NTILE; ++t) {
        half8 nx = *(const half8*)(bp + ((t + 1) & (NTILE - 1)) * 512);
        floatx16 d0 = __builtin_amdgcn_mfma_f32_32x32x16_f16(cur, qfr[0], czero, 0, 0, 0);
        floatx16 d1 = __builtin_amdgcn_mfma_f32_32x32x16_f16(cur, qfr[1], czero, 0, 0, 0);
        rv0 = vmin16(rv0, d0);
        rv1 = vmin16(rv1, d1);
        cur = nx;
    }

    // ---- Final tree (once) + h-half merge ----
    float rmq0 = fold16(rv0);
    float rmq1 = fold16(rv1);
    rmq0 = FMIN(rmq0, __shfl_xor(rmq0, 32, 64));
    rmq1 = FMIN(rmq1, __shfl_xor(rmq1, 32, 64));

    // ---- Emit: lane l owns query qb+l (h*32+m == l); coalesced write ----
    float* __restrict__ wsd = ws + (((size_t)chunk * 2 + dir) * B + b) * QCAP;
    const int idx = qb + l;
    const float val = h ? rmq1 : rmq0;
    if (idx < nq) wsd[idx] = val;
}

// Min over chunks + mean over queries. Blocks: (b, dir, qsplit of 4).
__global__ __launch_bounds__(256) void chamfer_reduce(const float* __restrict__ xyz1,
                                                      const float* __restrict__ xyz2,
                                                      const float* __restrict__ ws,
                                                      float* __restrict__ out,
                                                      int N, int M, int QCAP,
                                                      int nchunks) {
    const int b = (int)blockIdx.x, dir = (int)blockIdx.y;
    const int B = gridDim.x;
    const float* __restrict__ P = dir ? xyz2 + (size_t)b * M * 3 : xyz1 + (size_t)b * N * 3;
    const int nq = dir ? M : N;
    const size_t cs = (size_t)2 * B * QCAP;                       // chunk stride
    const float* __restrict__ w0 = ws + ((size_t)dir * B + b) * QCAP;

    float s = 0.0f;
    for (int q = (int)threadIdx.x + (int)blockIdx.z * 256; q < nq; q += 256 * (int)gridDim.z) {
        float v = w0[q];
        for (int c = 1; c < nchunks; ++c) v = FMIN(v, w0[c * cs + q]);
        float x = P[3 * q], y = P[3 * q + 1], z = P[3 * q + 2];
        s += v + 0.5f * (x * x + y * y + z * z);
    }
#pragma unroll
    for (int off = 32; off > 0; off >>= 1) s += __shfl_down(s, off, 64);
    __shared__ float red[4];
    if ((threadIdx.x & 63) == 0) red[threadIdx.x >> 6] = s;
    __syncthreads();
    if (threadIdx.x == 0) {
        float t = (red[0] + red[1]) + (red[2] + red[3]);
        atomicAdd(out + b, t * (2.0f / (float)nq));   // dist = 2*(ph + min acc)
    }
}

extern "C" void kernel_launch(void* const* d_in, const int* in_sizes, int n_in,
                              void* d_out, int out_size, void* d_ws, size_t ws_size,
                              hipStream_t stream) {
    const float* xyz1 = (const float*)d_in[0];
    const float* xyz2 = (const float*)d_in[1];
    float* out = (float*)d_out;

    const int B = out_size;
    const int N = in_sizes[0] / (3 * B);
    const int M = in_sizes[1] / (3 * B);

    hipMemsetAsync(d_out, 0, (size_t)B * sizeof(float), stream);

    const int qmax    = N > M ? N : M;
    const int qblocks = (qmax + QPB - 1) / QPB;
    const int QCAP    = ((qmax + 255) / 256) * 256;
    const int nchunks = (qmax + CHUNK - 1) / CHUNK;
    // ws usage: nchunks * 2 * B * QCAP * 4 bytes (= 4 MiB at B=32, QCAP=4096)

    dim3 grid(qblocks * nchunks, B, 2);
    chamfer_mfma<<<grid, dim3(TPB), 0, stream>>>(xyz1, xyz2, (float*)d_ws, N, M, QCAP, nchunks);
    chamfer_reduce<<<dim3(B, 2, 4), dim3(256), 0, stream>>>(xyz1, xyz2, (float*)d_ws, out, N, M, QCAP, nchunks);
}

// Round 19
// 97.398 us; speedup vs baseline: 1.6633x; 1.6633x over previous
//
#include <hip/hip_runtime.h>

typedef _Float16 half8 __attribute__((ext_vector_type(8)));
typedef float floatx16 __attribute__((ext_vector_type(16)));

#define TPB    256            // 4 waves
#define QPB    1024           // queries per block (256 per wave: 8 groups x 32)
#define CHUNK  1024           // db points per block (single-shot staged)
#define NTILE  (CHUNK / 32)   // 32 tiles of 32 db points
#define SMH    (CHUNK * 16)   // 16384 halfs = 32 KiB

// 32x32x16 f16 MFMA, SWAPPED-OPERAND form (R6): db points are the A operand
// (rows), queries are the B operand (cols). D col = lane&31 = query.
// R18: 8 QUERY-GROUPS PER WAVE. Grain amortization is the ONLY lever with a
// measured gain (R13->R16, 2->4 groups: +8%); all scheduling levers are null
// (occupancy R10, barriers R10, lag R14, prefetch depth R15, min encoding
// R13) and accumulator-vectorization REGRESSES (R17: floatx16 held across
// MFMAs -> AGPR churn, 2.7x). Per tile iter: 1 ds_read + 8 MFMA + 8 immediate
// scalar-tree folds, MFMA g+1 issued before fold g, only 2 floatx16 (dA/dB)
// transiently live — the one codegen shape proven clean.
// R17 lesson (REGRESSED 2.7x): NEVER hold floatx16 accumulators across MFMA
//   calls; fold immediately, scalar running mins only.
// R13 lesson (FMIN null): fminf already minnum; 1 min/distance is the floor.
// R7 lesson (FAILED): inline asm must never READ MFMA results (hazard gap).
// R9 lesson (REGRESSED): inline-asm v_min3 -> constraint copy-storm. NO asm.
// R4 lesson: no __launch_bounds__(256,8) — reg budget collapse -> spill.
// R1 lesson: staging data in named scalars; rmq as named scalars (no arrays).
// Block = 1024 queries x ONE md-chunk (1024 db points); partial per-query
// mins -> ws[chunk][dir][b][q]; chamfer_reduce mins over chunks + mean.
// K-slots (11 of 16): A(db): (xh,xl,xh,yh,yl,yh,zh,zl | zh,hqh,hql,0..)
//                     B(qry): (-xh,-xh,-xl,-yh,-yh,-yl,-zh,-zh | -zl,1,1,0..)
// => acc = 0.5||q_db||^2 - p.q_db (split-f16); dist = 2*(0.5||p||^2 + min acc).
// A: row = lane&31, k = (lane>>5)*8+j.  B: col = lane&31, same k.
// C/D: col = lane&31 (query), row(db) = (reg&3)+8*(reg>>2)+4*(lane>>5)
//   -> regs cover 16 of 32 db rows; h-partner lane covers the other 16.
// Emit: after h-merge, h=0 lanes write groups 0-3, h=1 lanes write groups 4-7.

#define FMIN __builtin_fminf   // llvm.minnum: single v_min_f32

// min of 16 accumulator regs (balanced tree, constant indices only)
__device__ __forceinline__ float fold16(floatx16 d) {
    float m0 = FMIN(FMIN(d[0],  d[1]),  d[2]);
    float m1 = FMIN(FMIN(d[3],  d[4]),  d[5]);
    float m2 = FMIN(FMIN(d[6],  d[7]),  d[8]);
    float m3 = FMIN(FMIN(d[9],  d[10]), d[11]);
    float m4 = FMIN(FMIN(d[12], d[13]), d[14]);
    float n0 = FMIN(FMIN(m0, m1), m2);
    float n1 = FMIN(FMIN(m3, m4), d[15]);
    return FMIN(n0, n1);
}

__device__ __forceinline__ void wr_point(_Float16* __restrict__ smb, int j,
                                         float x, float y, float z) {
    float hq = 0.5f * (x * x + y * y + z * z);
    _Float16 xh = (_Float16)x, yh = (_Float16)y, zh = (_Float16)z;
    _Float16 xl = (_Float16)(x - (float)xh);
    _Float16 yl = (_Float16)(y - (float)yh);
    _Float16 zl = (_Float16)(z - (float)zh);
    _Float16 qh = (_Float16)hq;
    _Float16 ql = (_Float16)(hq - (float)qh);
    const _Float16 hz = (_Float16)0.0f;
    int t = j >> 5, c = j & 31;
    half8 v0, v1;
    v0[0] = xh; v0[1] = xl; v0[2] = xh; v0[3] = yh;
    v0[4] = yl; v0[5] = yh; v0[6] = zh; v0[7] = zl;
    v1[0] = zh; v1[1] = qh; v1[2] = ql; v1[3] = hz;
    v1[4] = hz; v1[5] = hz; v1[6] = hz; v1[7] = hz;
    *(half8*)&smb[t * 512 + c * 8]       = v0;   // k-half 0
    *(half8*)&smb[t * 512 + 256 + c * 8] = v1;   // k-half 1
}

__global__ __launch_bounds__(TPB, 4) void chamfer_mfma(const float* __restrict__ xyz1,
                                                       const float* __restrict__ xyz2,
                                                       float* __restrict__ ws,
                                                       int N, int M, int QCAP,
                                                       int nchunks) {
    const int b = blockIdx.y, dir = blockIdx.z;
    const int B = gridDim.y;
    const int qblock = (int)blockIdx.x / nchunks;
    const int chunk  = (int)blockIdx.x % nchunks;
    const float* __restrict__ P = dir ? xyz2 + (size_t)b * M * 3 : xyz1 + (size_t)b * N * 3;
    const float* __restrict__ Q = dir ? xyz1 + (size_t)b * N * 3 : xyz2 + (size_t)b * M * 3;
    const int nq = dir ? M : N;
    const int md = dir ? N : M;

    if (qblock * QPB >= nq) return;   // block-uniform, before any barrier

    const int base = chunk * CHUNK;   // clamp-pad covers base+CHUNK > md

    __shared__ __align__(16) _Float16 smB[SMH];

    const int tid = (int)threadIdx.x;
    const int w   = tid >> 6;
    const int l   = tid & 63;
    const int m   = l & 31;      // B col (query) this lane serves
    const int h   = l >> 5;      // k-half: k = h*8 + j

    const _Float16 hz = (_Float16)0.0f, hone = (_Float16)1.0f;
    const int qb = qblock * QPB + w * 256;   // wave owns 256 queries (8 x 32)

    // ---- Build the wave's 8 query B-fragments (held for the whole kernel) ----
    half8 qfr[8];
#pragma unroll
    for (int g = 0; g < 8; ++g) {
        int idx = qb + g * 32 + m;
        int ci  = idx < nq ? idx : nq - 1;
        float x = P[3 * ci], y = P[3 * ci + 1], z = P[3 * ci + 2];
        _Float16 xh = (_Float16)x, yh = (_Float16)y, zh = (_Float16)z;
        _Float16 xl = (_Float16)(x - (float)xh);
        _Float16 yl = (_Float16)(y - (float)yh);
        _Float16 zl = (_Float16)(z - (float)zh);
        half8 a;
        if (h == 0) {
            a[0] = -xh; a[1] = -xh; a[2] = -xl; a[3] = -yh;
            a[4] = -yh; a[5] = -yl; a[6] = -zh; a[7] = -zh;
        } else {
            a[0] = -zl; a[1] = hone; a[2] = hone; a[3] = hz;
            a[4] = hz;  a[5] = hz;   a[6] = hz;  a[7] = hz;
        }
        qfr[g] = a;
    }

    // ---- Stage the whole 1024-pt chunk once (4 pts/thread, named scalars) ----
    {
        int g0 = base + tid;
        int g1 = base + tid + 256;
        int g2 = base + tid + 512;
        int g3 = base + tid + 768;
        g0 = g0 < md ? g0 : md - 1;   // clamp-pad: dups never change a min
        g1 = g1 < md ? g1 : md - 1;
        g2 = g2 < md ? g2 : md - 1;
        g3 = g3 < md ? g3 : md - 1;
        float x0 = Q[3 * g0], y0 = Q[3 * g0 + 1], z0 = Q[3 * g0 + 2];
        float x1 = Q[3 * g1], y1 = Q[3 * g1 + 1], z1 = Q[3 * g1 + 2];
        float x2 = Q[3 * g2], y2 = Q[3 * g2 + 1], z2 = Q[3 * g2 + 2];
        float x3 = Q[3 * g3], y3 = Q[3 * g3 + 1], z3 = Q[3 * g3 + 2];
        wr_point(smB, tid,       x0, y0, z0);
        wr_point(smB, tid + 256, x1, y1, z1);
        wr_point(smB, tid + 512, x2, y2, z2);
        wr_point(smB, tid + 768, x3, y3, z3);
    }
    __syncthreads();    // the kernel's ONLY barrier

    float rmq0 = 3.0e38f, rmq1 = 3.0e38f, rmq2 = 3.0e38f, rmq3 = 3.0e38f;
    float rmq4 = 3.0e38f, rmq5 = 3.0e38f, rmq6 = 3.0e38f, rmq7 = 3.0e38f;

    const floatx16 czero = {0.0f, 0.0f, 0.0f, 0.0f, 0.0f, 0.0f, 0.0f, 0.0f,
                            0.0f, 0.0f, 0.0f, 0.0f, 0.0f, 0.0f, 0.0f, 0.0f};

    // ---- Sweep 32 tiles: 1 ds_read (1-ahead) + 8 MFMA + 8 immediate folds.
    //      dA/dB ping-pong: MFMA g+1 in flight while fold g runs. ----
    const _Float16* bp = &smB[h * 256 + m * 8];
    half8 cur = *(const half8*)(bp);
#pragma unroll 1
    for (int t = 0; t < NTILE; ++t) {
        half8 nx = *(const half8*)(bp + ((t + 1) & (NTILE - 1)) * 512);
        floatx16 dA = __builtin_amdgcn_mfma_f32_32x32x16_f16(cur, qfr[0], czero, 0, 0, 0);
        floatx16 dB = __builtin_amdgcn_mfma_f32_32x32x16_f16(cur, qfr[1], czero, 0, 0, 0);
        rmq0 = FMIN(rmq0, fold16(dA));
        dA = __builtin_amdgcn_mfma_f32_32x32x16_f16(cur, qfr[2], czero, 0, 0, 0);
        rmq1 = FMIN(rmq1, fold16(dB));
        dB = __builtin_amdgcn_mfma_f32_32x32x16_f16(cur, qfr[3], czero, 0, 0, 0);
        rmq2 = FMIN(rmq2, fold16(dA));
        dA = __builtin_amdgcn_mfma_f32_32x32x16_f16(cur, qfr[4], czero, 0, 0, 0);
        rmq3 = FMIN(rmq3, fold16(dB));
        dB = __builtin_amdgcn_mfma_f32_32x32x16_f16(cur, qfr[5], czero, 0, 0, 0);
        rmq4 = FMIN(rmq4, fold16(dA));
        dA = __builtin_amdgcn_mfma_f32_32x32x16_f16(cur, qfr[6], czero, 0, 0, 0);
        rmq5 = FMIN(rmq5, fold16(dB));
        dB = __builtin_amdgcn_mfma_f32_32x32x16_f16(cur, qfr[7], czero, 0, 0, 0);
        rmq6 = FMIN(rmq6, fold16(dA));
        rmq7 = FMIN(rmq7, fold16(dB));
        cur = nx;
    }

    // ---- Merge h-halves (regs covered 16 of 32 db rows; partner has rest) ----
    rmq0 = FMIN(rmq0, __shfl_xor(rmq0, 32, 64));
    rmq1 = FMIN(rmq1, __shfl_xor(rmq1, 32, 64));
    rmq2 = FMIN(rmq2, __shfl_xor(rmq2, 32, 64));
    rmq3 = FMIN(rmq3, __shfl_xor(rmq3, 32, 64));
    rmq4 = FMIN(rmq4, __shfl_xor(rmq4, 32, 64));
    rmq5 = FMIN(rmq5, __shfl_xor(rmq5, 32, 64));
    rmq6 = FMIN(rmq6, __shfl_xor(rmq6, 32, 64));
    rmq7 = FMIN(rmq7, __shfl_xor(rmq7, 32, 64));

    // ---- Emit: h=0 lanes write groups 0-3; h=1 lanes write groups 4-7 ----
    float* __restrict__ wsd = ws + (((size_t)chunk * 2 + dir) * B + b) * QCAP;
    const int ibase = qb + h * 128 + m;
    const float v0 = h ? rmq4 : rmq0;
    const float v1 = h ? rmq5 : rmq1;
    const float v2 = h ? rmq6 : rmq2;
    const float v3 = h ? rmq7 : rmq3;
    if (ibase      < nq) wsd[ibase]      = v0;
    if (ibase + 32 < nq) wsd[ibase + 32] = v1;
    if (ibase + 64 < nq) wsd[ibase + 64] = v2;
    if (ibase + 96 < nq) wsd[ibase + 96] = v3;
}

// Min over chunks + mean over queries. Blocks: (b, dir, qsplit of 4).
__global__ __launch_bounds__(256) void chamfer_reduce(const float* __restrict__ xyz1,
                                                      const float* __restrict__ xyz2,
                                                      const float* __restrict__ ws,
                                                      float* __restrict__ out,
                                                      int N, int M, int QCAP,
                                                      int nchunks) {
    const int b = (int)blockIdx.x, dir = (int)blockIdx.y;
    const int B = gridDim.x;
    const float* __restrict__ P = dir ? xyz2 + (size_t)b * M * 3 : xyz1 + (size_t)b * N * 3;
    const int nq = dir ? M : N;
    const size_t cs = (size_t)2 * B * QCAP;                       // chunk stride
    const float* __restrict__ w0 = ws + ((size_t)dir * B + b) * QCAP;

    float s = 0.0f;
    for (int q = (int)threadIdx.x + (int)blockIdx.z * 256; q < nq; q += 256 * (int)gridDim.z) {
        float v = w0[q];
        for (int c = 1; c < nchunks; ++c) v = FMIN(v, w0[c * cs + q]);
        float x = P[3 * q], y = P[3 * q + 1], z = P[3 * q + 2];
        s += v + 0.5f * (x * x + y * y + z * z);
    }
#pragma unroll
    for (int off = 32; off > 0; off >>= 1) s += __shfl_down(s, off, 64);
    __shared__ float red[4];
    if ((threadIdx.x & 63) == 0) red[threadIdx.x >> 6] = s;
    __syncthreads();
    if (threadIdx.x == 0) {
        float t = (red[0] + red[1]) + (red[2] + red[3]);
        atomicAdd(out + b, t * (2.0f / (float)nq));   // dist = 2*(ph + min acc)
    }
}

extern "C" void kernel_launch(void* const* d_in, const int* in_sizes, int n_in,
                              void* d_out, int out_size, void* d_ws, size_t ws_size,
                              hipStream_t stream) {
    const float* xyz1 = (const float*)d_in[0];
    const float* xyz2 = (const float*)d_in[1];
    float* out = (float*)d_out;

    const int B = out_size;
    const int N = in_sizes[0] / (3 * B);
    const int M = in_sizes[1] / (3 * B);

    hipMemsetAsync(d_out, 0, (size_t)B * sizeof(float), stream);

    const int qmax    = N > M ? N : M;
    const int qblocks = (qmax + QPB - 1) / QPB;
    const int QCAP    = ((qmax + 255) / 256) * 256;
    const int nchunks = (qmax + CHUNK - 1) / CHUNK;
    // ws usage: nchunks * 2 * B * QCAP * 4 bytes (= 4 MiB at B=32, QCAP=4096)

    dim3 grid(qblocks * nchunks, B, 2);
    chamfer_mfma<<<grid, dim3(TPB), 0, stream>>>(xyz1, xyz2, (float*)d_ws, N, M, QCAP, nchunks);
    chamfer_reduce<<<dim3(B, 2, 4), dim3(256), 0, stream>>>(xyz1, xyz2, (float*)d_ws, out, N, M, QCAP, nchunks);
}

// Round 20
// 97.096 us; speedup vs baseline: 1.6685x; 1.0031x over previous
//
#include <hip/hip_runtime.h>

typedef _Float16 half8 __attribute__((ext_vector_type(8)));
typedef float floatx16 __attribute__((ext_vector_type(16)));

#define TPB    256            // 4 waves
#define QPB    1024           // queries per block (256 per wave: 8 groups x 32)
#define CHUNK  1024           // db points per block (single-shot staged)
#define NTILE  (CHUNK / 32)   // 32 tiles of 32 db points
#define SMH    (CHUNK * 16)   // 16384 halfs = 32 KiB

// 32x32x16 f16 MFMA, SWAPPED-OPERAND form (R6): db points are the A operand
// (rows), queries are the B operand (cols). D col = lane&31 = query.
// R20: 4-DEEP MFMA LEAD + sched_group_barrier PINNING. Ledger after R19:
// bench = ~54us fixed harness overhead (268MB ws poison-fill = 41us) + ~43us
// kernels; main kernel sits at ~2x its 13.7us fold floor. Last coherent
// stall theory: MFMA->VALU result-read hazard (~34-64cyc) — every fold's
// first min reads an accumulator written ~8-40cyc earlier. R14/R15 tried to
// lag the fold at source level and the machine scheduler COLLAPSED it
// (VGPR=44 both times). sched_group_barrier is the one tool that constrains
// that exact reordering without routing data through asm (R7/R9 bans):
// per-iter pin = DS_READ 1, MFMA 4, (VALU 16, MFMA 1) x4, VALU 64.
// e0..e3 = 4 live floatx16 (64 VGPR); no rm-array, so NOT R3's spill config.
// Est ~120 VGPR. Tripwire: WRITE_SIZE >> 10MB = spill -> revert to R16.
// R19 lesson: grain flat 4->8 groups; overhead already amortized.
// R17 lesson (REGRESSED 2.7x): NEVER hold floatx16 accumulators ACROSS tile
//   iterations (AGPR churn); within-iteration transients are fine.
// R13 lesson (FMIN null): fminf already minnum; 1 min/distance is the floor.
// R7 lesson (FAILED): inline asm must never READ MFMA results (hazard gap).
// R9 lesson (REGRESSED): inline-asm v_min3 -> constraint copy-storm. NO asm.
// R4 lesson: no __launch_bounds__(256,8) — reg budget collapse -> spill.
// R1 lesson: staging data in named scalars; rmq as named scalars (no arrays).
// Block = 1024 queries x ONE md-chunk (1024 db points); partial per-query
// mins -> ws[chunk][dir][b][q]; chamfer_reduce mins over chunks + mean.
// K-slots (11 of 16): A(db): (xh,xl,xh,yh,yl,yh,zh,zl | zh,hqh,hql,0..)
//                     B(qry): (-xh,-xh,-xl,-yh,-yh,-yl,-zh,-zh | -zl,1,1,0..)
// => acc = 0.5||q_db||^2 - p.q_db (split-f16); dist = 2*(0.5||p||^2 + min acc).
// A: row = lane&31, k = (lane>>5)*8+j.  B: col = lane&31, same k.
// C/D: col = lane&31 (query), row(db) = (reg&3)+8*(reg>>2)+4*(lane>>5)
//   -> regs cover 16 of 32 db rows; h-partner lane covers the other 16.
// Emit: after h-merge, h=0 lanes write groups 0-3, h=1 lanes write groups 4-7.

#define FMIN __builtin_fminf   // llvm.minnum: single v_min_f32

// sched_group_barrier masks (LLVM SchedGroupMask)
#define SGB(mask, n) __builtin_amdgcn_sched_group_barrier((mask), (n), 0)
#define SG_VALU    0x2
#define SG_MFMA    0x8
#define SG_DSREAD  0x100

// min of 16 accumulator regs (balanced tree, constant indices only)
__device__ __forceinline__ float fold16(floatx16 d) {
    float m0 = FMIN(FMIN(d[0],  d[1]),  d[2]);
    float m1 = FMIN(FMIN(d[3],  d[4]),  d[5]);
    float m2 = FMIN(FMIN(d[6],  d[7]),  d[8]);
    float m3 = FMIN(FMIN(d[9],  d[10]), d[11]);
    float m4 = FMIN(FMIN(d[12], d[13]), d[14]);
    float n0 = FMIN(FMIN(m0, m1), m2);
    float n1 = FMIN(FMIN(m3, m4), d[15]);
    return FMIN(n0, n1);
}

__device__ __forceinline__ void wr_point(_Float16* __restrict__ smb, int j,
                                         float x, float y, float z) {
    float hq = 0.5f * (x * x + y * y + z * z);
    _Float16 xh = (_Float16)x, yh = (_Float16)y, zh = (_Float16)z;
    _Float16 xl = (_Float16)(x - (float)xh);
    _Float16 yl = (_Float16)(y - (float)yh);
    _Float16 zl = (_Float16)(z - (float)zh);
    _Float16 qh = (_Float16)hq;
    _Float16 ql = (_Float16)(hq - (float)qh);
    const _Float16 hz = (_Float16)0.0f;
    int t = j >> 5, c = j & 31;
    half8 v0, v1;
    v0[0] = xh; v0[1] = xl; v0[2] = xh; v0[3] = yh;
    v0[4] = yl; v0[5] = yh; v0[6] = zh; v0[7] = zl;
    v1[0] = zh; v1[1] = qh; v1[2] = ql; v1[3] = hz;
    v1[4] = hz; v1[5] = hz; v1[6] = hz; v1[7] = hz;
    *(half8*)&smb[t * 512 + c * 8]       = v0;   // k-half 0
    *(half8*)&smb[t * 512 + 256 + c * 8] = v1;   // k-half 1
}

__global__ __launch_bounds__(TPB, 4) void chamfer_mfma(const float* __restrict__ xyz1,
                                                       const float* __restrict__ xyz2,
                                                       float* __restrict__ ws,
                                                       int N, int M, int QCAP,
                                                       int nchunks) {
    const int b = blockIdx.y, dir = blockIdx.z;
    const int B = gridDim.y;
    const int qblock = (int)blockIdx.x / nchunks;
    const int chunk  = (int)blockIdx.x % nchunks;
    const float* __restrict__ P = dir ? xyz2 + (size_t)b * M * 3 : xyz1 + (size_t)b * N * 3;
    const float* __restrict__ Q = dir ? xyz1 + (size_t)b * N * 3 : xyz2 + (size_t)b * M * 3;
    const int nq = dir ? M : N;
    const int md = dir ? N : M;

    if (qblock * QPB >= nq) return;   // block-uniform, before any barrier

    const int base = chunk * CHUNK;   // clamp-pad covers base+CHUNK > md

    __shared__ __align__(16) _Float16 smB[SMH];

    const int tid = (int)threadIdx.x;
    const int w   = tid >> 6;
    const int l   = tid & 63;
    const int m   = l & 31;      // B col (query) this lane serves
    const int h   = l >> 5;      // k-half: k = h*8 + j

    const _Float16 hz = (_Float16)0.0f, hone = (_Float16)1.0f;
    const int qb = qblock * QPB + w * 256;   // wave owns 256 queries (8 x 32)

    // ---- Build the wave's 8 query B-fragments (held for the whole kernel) ----
    half8 qfr[8];
#pragma unroll
    for (int g = 0; g < 8; ++g) {
        int idx = qb + g * 32 + m;
        int ci  = idx < nq ? idx : nq - 1;
        float x = P[3 * ci], y = P[3 * ci + 1], z = P[3 * ci + 2];
        _Float16 xh = (_Float16)x, yh = (_Float16)y, zh = (_Float16)z;
        _Float16 xl = (_Float16)(x - (float)xh);
        _Float16 yl = (_Float16)(y - (float)yh);
        _Float16 zl = (_Float16)(z - (float)zh);
        half8 a;
        if (h == 0) {
            a[0] = -xh; a[1] = -xh; a[2] = -xl; a[3] = -yh;
            a[4] = -yh; a[5] = -yl; a[6] = -zh; a[7] = -zh;
        } else {
            a[0] = -zl; a[1] = hone; a[2] = hone; a[3] = hz;
            a[4] = hz;  a[5] = hz;   a[6] = hz;  a[7] = hz;
        }
        qfr[g] = a;
    }

    // ---- Stage the whole 1024-pt chunk once (4 pts/thread, named scalars) ----
    {
        int g0 = base + tid;
        int g1 = base + tid + 256;
        int g2 = base + tid + 512;
        int g3 = base + tid + 768;
        g0 = g0 < md ? g0 : md - 1;   // clamp-pad: dups never change a min
        g1 = g1 < md ? g1 : md - 1;
        g2 = g2 < md ? g2 : md - 1;
        g3 = g3 < md ? g3 : md - 1;
        float x0 = Q[3 * g0], y0 = Q[3 * g0 + 1], z0 = Q[3 * g0 + 2];
        float x1 = Q[3 * g1], y1 = Q[3 * g1 + 1], z1 = Q[3 * g1 + 2];
        float x2 = Q[3 * g2], y2 = Q[3 * g2 + 1], z2 = Q[3 * g2 + 2];
        float x3 = Q[3 * g3], y3 = Q[3 * g3 + 1], z3 = Q[3 * g3 + 2];
        wr_point(smB, tid,       x0, y0, z0);
        wr_point(smB, tid + 256, x1, y1, z1);
        wr_point(smB, tid + 512, x2, y2, z2);
        wr_point(smB, tid + 768, x3, y3, z3);
    }
    __syncthreads();    // the kernel's ONLY barrier

    float rmq0 = 3.0e38f, rmq1 = 3.0e38f, rmq2 = 3.0e38f, rmq3 = 3.0e38f;
    float rmq4 = 3.0e38f, rmq5 = 3.0e38f, rmq6 = 3.0e38f, rmq7 = 3.0e38f;

    const floatx16 czero = {0.0f, 0.0f, 0.0f, 0.0f, 0.0f, 0.0f, 0.0f, 0.0f,
                            0.0f, 0.0f, 0.0f, 0.0f, 0.0f, 0.0f, 0.0f, 0.0f};

    // ---- Sweep 32 tiles: 4-deep MFMA lead. Each fold trails its producing
    //      MFMA by >=3 MFMA issues + ~2 folds (~90+ cyc > 34-64cyc hazard).
    //      SGB sequence pins the interleave against scheduler collapse. ----
    const _Float16* bp = &smB[h * 256 + m * 8];
    half8 cur = *(const half8*)(bp);
#pragma unroll 1
    for (int t = 0; t < NTILE; ++t) {
        half8 nx = *(const half8*)(bp + ((t + 1) & (NTILE - 1)) * 512);
        floatx16 e0 = __builtin_amdgcn_mfma_f32_32x32x16_f16(cur, qfr[0], czero, 0, 0, 0);
        floatx16 e1 = __builtin_amdgcn_mfma_f32_32x32x16_f16(cur, qfr[1], czero, 0, 0, 0);
        floatx16 e2 = __builtin_amdgcn_mfma_f32_32x32x16_f16(cur, qfr[2], czero, 0, 0, 0);
        floatx16 e3 = __builtin_amdgcn_mfma_f32_32x32x16_f16(cur, qfr[3], czero, 0, 0, 0);
        rmq0 = FMIN(rmq0, fold16(e0));
        e0 = __builtin_amdgcn_mfma_f32_32x32x16_f16(cur, qfr[4], czero, 0, 0, 0);
        rmq1 = FMIN(rmq1, fold16(e1));
        e1 = __builtin_amdgcn_mfma_f32_32x32x16_f16(cur, qfr[5], czero, 0, 0, 0);
        rmq2 = FMIN(rmq2, fold16(e2));
        e2 = __builtin_amdgcn_mfma_f32_32x32x16_f16(cur, qfr[6], czero, 0, 0, 0);
        rmq3 = FMIN(rmq3, fold16(e3));
        e3 = __builtin_amdgcn_mfma_f32_32x32x16_f16(cur, qfr[7], czero, 0, 0, 0);
        rmq4 = FMIN(rmq4, fold16(e0));
        rmq5 = FMIN(rmq5, fold16(e1));
        rmq6 = FMIN(rmq6, fold16(e2));
        rmq7 = FMIN(rmq7, fold16(e3));
        cur = nx;

        // Pin: ds_read first, 4-MFMA burst, then fold/MFMA interleave.
        SGB(SG_DSREAD, 1);
        SGB(SG_MFMA, 4);
        SGB(SG_VALU, 16); SGB(SG_MFMA, 1);
        SGB(SG_VALU, 16); SGB(SG_MFMA, 1);
        SGB(SG_VALU, 16); SGB(SG_MFMA, 1);
        SGB(SG_VALU, 16); SGB(SG_MFMA, 1);
        SGB(SG_VALU, 64);
    }

    // ---- Merge h-halves (regs covered 16 of 32 db rows; partner has rest) ----
    rmq0 = FMIN(rmq0, __shfl_xor(rmq0, 32, 64));
    rmq1 = FMIN(rmq1, __shfl_xor(rmq1, 32, 64));
    rmq2 = FMIN(rmq2, __shfl_xor(rmq2, 32, 64));
    rmq3 = FMIN(rmq3, __shfl_xor(rmq3, 32, 64));
    rmq4 = FMIN(rmq4, __shfl_xor(rmq4, 32, 64));
    rmq5 = FMIN(rmq5, __shfl_xor(rmq5, 32, 64));
    rmq6 = FMIN(rmq6, __shfl_xor(rmq6, 32, 64));
    rmq7 = FMIN(rmq7, __shfl_xor(rmq7, 32, 64));

    // ---- Emit: h=0 lanes write groups 0-3; h=1 lanes write groups 4-7 ----
    float* __restrict__ wsd = ws + (((size_t)chunk * 2 + dir) * B + b) * QCAP;
    const int ibase = qb + h * 128 + m;
    const float v0 = h ? rmq4 : rmq0;
    const float v1 = h ? rmq5 : rmq1;
    const float v2 = h ? rmq6 : rmq2;
    const float v3 = h ? rmq7 : rmq3;
    if (ibase      < nq) wsd[ibase]      = v0;
    if (ibase + 32 < nq) wsd[ibase + 32] = v1;
    if (ibase + 64 < nq) wsd[ibase + 64] = v2;
    if (ibase + 96 < nq) wsd[ibase + 96] = v3;
}

// Min over chunks + mean over queries. Blocks: (b, dir, qsplit of 4).
__global__ __launch_bounds__(256) void chamfer_reduce(const float* __restrict__ xyz1,
                                                      const float* __restrict__ xyz2,
                                                      const float* __restrict__ ws,
                                                      float* __restrict__ out,
                                                      int N, int M, int QCAP,
                                                      int nchunks) {
    const int b = (int)blockIdx.x, dir = (int)blockIdx.y;
    const int B = gridDim.x;
    const float* __restrict__ P = dir ? xyz2 + (size_t)b * M * 3 : xyz1 + (size_t)b * N * 3;
    const int nq = dir ? M : N;
    const size_t cs = (size_t)2 * B * QCAP;                       // chunk stride
    const float* __restrict__ w0 = ws + ((size_t)dir * B + b) * QCAP;

    float s = 0.0f;
    for (int q = (int)threadIdx.x + (int)blockIdx.z * 256; q < nq; q += 256 * (int)gridDim.z) {
        float v = w0[q];
        for (int c = 1; c < nchunks; ++c) v = FMIN(v, w0[c * cs + q]);
        float x = P[3 * q], y = P[3 * q + 1], z = P[3 * q + 2];
        s += v + 0.5f * (x * x + y * y + z * z);
    }
#pragma unroll
    for (int off = 32; off > 0; off >>= 1) s += __shfl_down(s, off, 64);
    __shared__ float red[4];
    if ((threadIdx.x & 63) == 0) red[threadIdx.x >> 6] = s;
    __syncthreads();
    if (threadIdx.x == 0) {
        float t = (red[0] + red[1]) + (red[2] + red[3]);
        atomicAdd(out + b, t * (2.0f / (float)nq));   // dist = 2*(ph + min acc)
    }
}

extern "C" void kernel_launch(void* const* d_in, const int* in_sizes, int n_in,
                              void* d_out, int out_size, void* d_ws, size_t ws_size,
                              hipStream_t stream) {
    const float* xyz1 = (const float*)d_in[0];
    const float* xyz2 = (const float*)d_in[1];
    float* out = (float*)d_out;

    const int B = out_size;
    const int N = in_sizes[0] / (3 * B);
    const int M = in_sizes[1] / (3 * B);

    hipMemsetAsync(d_out, 0, (size_t)B * sizeof(float), stream);

    const int qmax    = N > M ? N : M;
    const int qblocks = (qmax + QPB - 1) / QPB;
    const int QCAP    = ((qmax + 255) / 256) * 256;
    const int nchunks = (qmax + CHUNK - 1) / CHUNK;
    // ws usage: nchunks * 2 * B * QCAP * 4 bytes (= 4 MiB at B=32, QCAP=4096)

    dim3 grid(qblocks * nchunks, B, 2);
    chamfer_mfma<<<grid, dim3(TPB), 0, stream>>>(xyz1, xyz2, (float*)d_ws, N, M, QCAP, nchunks);
    chamfer_reduce<<<dim3(B, 2, 4), dim3(256), 0, stream>>>(xyz1, xyz2, (float*)d_ws, out, N, M, QCAP, nchunks);
}